// Round 5
// baseline (1559.860 us; speedup 1.0000x reference)
//
#include <hip/hip_runtime.h>
#include <math.h>

#define Dz 16
#define Hy 64
#define Wx 64
#define CHN 256
#define NVOX (Dz*Hy*Wx)      // 65536
#define TOPK 2048
#define MAXOUT 256
#define CAND_CAP 4096
#define NBCAP 16
#define NHIST 65536

typedef __attribute__((ext_vector_type(8))) _Float16 h8;
typedef __attribute__((ext_vector_type(8))) unsigned short u16x8;
typedef __attribute__((ext_vector_type(4))) float f32x4;

__device__ __forceinline__ float gelu_tanh(float x) {
    return 0.5f*x*(1.0f + tanhf(0.7978845608028654f*(x + 0.044715f*x*x*x)));
}
__device__ __forceinline__ unsigned f2sort(float f) {
    unsigned u = __float_as_uint(f);
    return (u & 0x80000000u) ? ~u : (u | 0x80000000u);
}
__device__ __forceinline__ float sort2f(unsigned s) {
    unsigned u = (s & 0x80000000u) ? (s & 0x7fffffffu) : ~s;
    return __uint_as_float(u);
}

#define MFMA(d, a, b) d = __builtin_amdgcn_mfma_f32_16x16x32_f16(a, b, d, 0, 0, 0)

__device__ __forceinline__ void gl_lds16(const void* g, void* l) {
    __builtin_amdgcn_global_load_lds(
        (const __attribute__((address_space(1))) void*)g,
        (__attribute__((address_space(3))) void*)l, 16, 0, 0);
}

// ---------------------------------------------------------------------------
// prep: pack weights (f32 -> per-lane MFMA B-fragment f16 hi/lo, layout
// chunk = (((tap*8+kbg)*16+ng)*2+plane)*64 + lane) + zero hist/counter/zerobuf
// ---------------------------------------------------------------------------
__global__ __launch_bounds__(256) void prep_kernel(const float* __restrict__ w0,
        const float* __restrict__ w1, u16x8* __restrict__ wpk0,
        u16x8* __restrict__ wpk1, unsigned* __restrict__ hist,
        unsigned* __restrict__ counter, float4* __restrict__ zerob) {
    int b = blockIdx.x, t = threadIdx.x;
    if (b < 1728) {
        int id = b*256 + t;                       // 442368 total
        int l = (id >= 221184) ? 1 : 0;
        int r = id - l*221184;
        int lane = r & 63, ng = (r >> 6) & 15, kbg = (r >> 10) & 7, tp = r >> 13;
        const float* w = l ? w1 : w0;
        u16x8* dst = l ? wpk1 : wpk0;
        h8 hv, lv;
        #pragma unroll
        for (int j = 0; j < 8; ++j) {
            int k = kbg*32 + (lane >> 4)*8 + j;
            int co = ng*16 + (lane & 15);
            float v = w[((size_t)tp*CHN + k)*CHN + co];
            _Float16 h = (_Float16)v;
            hv[j] = h;
            lv[j] = (_Float16)(v - (float)h);
        }
        size_t base = (((size_t)(tp*8 + kbg)*16 + ng)*2)*64 + lane;
        dst[base]      = __builtin_bit_cast(u16x8, hv);
        dst[base + 64] = __builtin_bit_cast(u16x8, lv);
    } else {
        int zb = b - 1728;                        // 0..63
        int i = zb*256 + t;                       // 0..16383
        hist[i] = 0u; hist[i + 16384] = 0u; hist[i + 32768] = 0u; hist[i + 49152] = 0u;
        if (zb == 0 && t == 0) counter[0] = 0u;
        if (zb == 0 && t == 2) *zerob = make_float4(0.f, 0.f, 0.f, 0.f);
    }
}

// ---------------------------------------------------------------------------
// Conv as MFMA GEMM, staged with global_load_lds (linear LDS dest, swizzled
// per-lane global source; OOB lanes read a zero buffer).
// LAYER 0: LDS tile = raw f32 [iy4][r66][slot16], slot = c ^ ((r&7)<<1);
//          f16 hi/lo split happens at fragment-load time (exact, RNE).
// LAYER 1: LDS tile = f16 [plane2][iy4][r66][slot8], slot = c ^ (r&7).
// Both: 4224 x 16B chunks = 67584 B, 12 phases (dz x kc), block = 128 vox.
// ---------------------------------------------------------------------------
template<int LAYER>
__device__ __forceinline__ void stage_chunk(int cidx, void* ldst,
        const float* f32in, const unsigned short* hhi, const unsigned short* hlo,
        const float4* zerob, int zz, bool zok, int y0, int kc) {
    const void* src;
    if (LAYER == 0) {
        int c = cidx & 15, rr = cidx >> 4;
        int r = rr % 66, iy = rr / 66;
        int ygl = y0 - 1 + iy, xin = r - 1;
        bool ok = zok & ((unsigned)ygl < (unsigned)Hy) & ((unsigned)xin < (unsigned)Wx);
        int cs = c ^ ((r & 7) << 1);
        src = ok ? (const void*)(f32in + ((size_t)(((size_t)zz*Hy + ygl)*Wx + xin))*CHN
                                 + kc*64 + cs*4)
                 : (const void*)zerob;
    } else {
        int c = cidx & 7, rr = cidx >> 3;
        int r = rr % 66, tt = rr / 66;
        int p = tt >> 2, iy = tt & 3;
        int ygl = y0 - 1 + iy, xin = r - 1;
        bool ok = zok & ((unsigned)ygl < (unsigned)Hy) & ((unsigned)xin < (unsigned)Wx);
        int cs = c ^ (r & 7);
        const unsigned short* bp = p ? hlo : hhi;
        src = ok ? (const void*)(bp + ((size_t)(((size_t)zz*Hy + ygl)*Wx + xin))*CHN
                                 + kc*64 + cs*8)
                 : (const void*)zerob;
    }
    gl_lds16(src, ldst);
}

template<int LAYER>
__global__ __launch_bounds__(512, 4) void conv_kernel(
        const float* __restrict__ f32in,
        const unsigned short* __restrict__ hhi, const unsigned short* __restrict__ hlo,
        const u16x8* __restrict__ wpk, const float* __restrict__ bias,
        const float4* __restrict__ zerob,
        unsigned short* __restrict__ ohi, unsigned short* __restrict__ olo,
        const float* __restrict__ wlog, const float* __restrict__ blog,
        const float* __restrict__ wreg, const float* __restrict__ breg,
        float* __restrict__ locs, unsigned long long* __restrict__ keys,
        unsigned* __restrict__ hist) {
    __shared__ h8 sm[4224];                       // 67584 B
    const int tid = threadIdx.x;
    const int lane = tid & 63, w = tid >> 6;
    const int yo = w >> 2, wn = w & 3;
    const int lr = lane & 15, lg = lane >> 4;
    const int z = blockIdx.y, y0 = blockIdx.x*2;
    const int wbs = tid & ~63;

    f32x4 acc[4][4];
    #pragma unroll
    for (int m = 0; m < 4; ++m)
        #pragma unroll
        for (int n = 0; n < 4; ++n) acc[m][n] = (f32x4){0.f,0.f,0.f,0.f};

    for (int dz = 0; dz < 3; ++dz) {
        const int zz = z + dz - 1;
        const bool zok = (unsigned)zz < (unsigned)Dz;
        for (int kc = 0; kc < 4; ++kc) {
            __syncthreads();               // prior phase's readers done
            #pragma unroll
            for (int k = 0; k < 8; ++k)
                stage_chunk<LAYER>(k*512 + tid, (void*)&sm[k*512 + wbs],
                                   f32in, hhi, hlo, zerob, zz, zok, y0, kc);
            if (tid < 128)                 // tail 128 chunks (waves 0,1 fully)
                stage_chunk<LAYER>(4096 + tid, (void*)&sm[4096 + wbs],
                                   f32in, hhi, hlo, zerob, zz, zok, y0, kc);
            asm volatile("s_waitcnt vmcnt(0)" ::: "memory");
            __syncthreads();               // all staging landed
            // ---------------- compute: 9 taps x 2 kb ----------------
            for (int dy = 0; dy < 3; ++dy) {
                const int iyA = yo + dy;
                #pragma unroll
                for (int dx = 0; dx < 3; ++dx) {
                    const int tap = (dz*3 + dy)*3 + dx;
                    #pragma unroll
                    for (int kb = 0; kb < 2; ++kb) {
                        const int kbg = kc*2 + kb;
                        const u16x8* wb = wpk + ((size_t)(tap*8 + kbg)*32 + wn*8)*64 + lane;
                        h8 bh[4];
                        #pragma unroll
                        for (int n = 0; n < 4; ++n)
                            bh[n] = __builtin_bit_cast(h8, wb[(size_t)n*128]);
                        #pragma unroll
                        for (int m = 0; m < 4; ++m) {
                            const int r = m*16 + lr + dx;
                            h8 ah, al;
                            if (LAYER == 0) {
                                const f32x4* Af = (const f32x4*)sm + ((size_t)iyA*66 + r)*16;
                                int s0 = (kb*8 + lg*2) ^ ((r & 7) << 1);
                                f32x4 a0 = Af[s0], a1 = Af[s0 | 1];
                                #pragma unroll
                                for (int j = 0; j < 4; ++j) {
                                    _Float16 h0 = (_Float16)a0[j];
                                    ah[j] = h0; al[j] = (_Float16)(a0[j] - (float)h0);
                                    _Float16 h1 = (_Float16)a1[j];
                                    ah[4+j] = h1; al[4+j] = (_Float16)(a1[j] - (float)h1);
                                }
                            } else {
                                const int sl = (kb*4 + lg) ^ (r & 7);
                                ah = sm[((size_t)iyA*66 + r)*8 + sl];
                                al = sm[2112 + ((size_t)iyA*66 + r)*8 + sl];
                            }
                            #pragma unroll
                            for (int n = 0; n < 4; ++n) {
                                MFMA(acc[m][n], ah, bh[n]);
                                MFMA(acc[m][n], al, bh[n]);
                            }
                        }
                        h8 bl[4];
                        #pragma unroll
                        for (int n = 0; n < 4; ++n)
                            bl[n] = __builtin_bit_cast(h8, wb[(size_t)n*128 + 64]);
                        #pragma unroll
                        for (int m = 0; m < 4; ++m) {
                            const int r = m*16 + lr + dx;
                            h8 ah;
                            if (LAYER == 0) {
                                const f32x4* Af = (const f32x4*)sm + ((size_t)iyA*66 + r)*16;
                                int s0 = (kb*8 + lg*2) ^ ((r & 7) << 1);
                                f32x4 a0 = Af[s0], a1 = Af[s0 | 1];
                                #pragma unroll
                                for (int j = 0; j < 4; ++j) {
                                    ah[j] = (_Float16)a0[j];
                                    ah[4+j] = (_Float16)a1[j];
                                }
                            } else {
                                const int sl = (kb*4 + lg) ^ (r & 7);
                                ah = sm[((size_t)iyA*66 + r)*8 + sl];
                            }
                            #pragma unroll
                            for (int n = 0; n < 4; ++n) MFMA(acc[m][n], ah, bl[n]);
                        }
                    }
                }
            }
        }
    }

    // ------------------------------ epilogue ------------------------------
    float bn[4];
    #pragma unroll
    for (int n = 0; n < 4; ++n) bn[n] = bias[wn*64 + n*16 + lr];

    if (LAYER == 0) {
        const int ygl = y0 + yo;
        #pragma unroll
        for (int m = 0; m < 4; ++m) {
            #pragma unroll
            for (int rg = 0; rg < 4; ++rg) {
                const int x = m*16 + lg*4 + rg;
                const size_t vbase = ((size_t)((z*Hy + ygl)*Wx + x))*CHN;
                #pragma unroll
                for (int n = 0; n < 4; ++n) {
                    const int co = wn*64 + n*16 + lr;
                    float g = gelu_tanh(acc[m][n][rg] + bn[n]);
                    _Float16 h = (_Float16)g;
                    _Float16 l = (_Float16)(g - (float)h);
                    ohi[vbase + co] = __builtin_bit_cast(unsigned short, h);
                    olo[vbase + co] = __builtin_bit_cast(unsigned short, l);
                }
            }
        }
    } else {
        // detection head from registers: per-lane partial dots over its 4 cos
        float wl[4], wr0[4], wr1[4], wr2[4];
        #pragma unroll
        for (int n = 0; n < 4; ++n) {
            const int co = wn*64 + n*16 + lr;
            wl[n] = wlog[co];
            wr0[n] = wreg[co*3 + 0]; wr1[n] = wreg[co*3 + 1]; wr2[n] = wreg[co*3 + 2];
        }
        float p[4][16];
        #pragma unroll
        for (int c = 0; c < 4; ++c)
            #pragma unroll
            for (int xi = 0; xi < 16; ++xi) p[c][xi] = 0.f;
        #pragma unroll
        for (int m = 0; m < 4; ++m)
            #pragma unroll
            for (int rg = 0; rg < 4; ++rg) {
                const int xi = m*4 + rg;
                #pragma unroll
                for (int n = 0; n < 4; ++n) {
                    float g = gelu_tanh(acc[m][n][rg] + bn[n]);
                    p[0][xi] += g*wl[n];
                    p[1][xi] += g*wr0[n];
                    p[2][xi] += g*wr1[n];
                    p[3][xi] += g*wr2[n];
                }
            }
        #pragma unroll
        for (int st = 0; st < 4; ++st) {
            const int s = 1 << st;
            #pragma unroll
            for (int c = 0; c < 4; ++c)
                #pragma unroll
                for (int xi = 0; xi < 16; ++xi)
                    p[c][xi] += __shfl_xor(p[c][xi], s, 64);
        }
        __syncthreads();                 // stage buffer dead -> reuse as det
        float* det = (float*)sm;         // [2][64][4][4] = 8 KB
        if (lr == 0) {
            #pragma unroll
            for (int m = 0; m < 4; ++m)
                #pragma unroll
                for (int rg = 0; rg < 4; ++rg) {
                    const int x = m*16 + lg*4 + rg;
                    #pragma unroll
                    for (int c = 0; c < 4; ++c)
                        det[((yo*64 + x)*4 + c)*4 + wn] = p[c][m*4 + rg];
                }
        }
        __syncthreads();
        {
            const int yo2 = tid >> 8, x = (tid >> 2) & 63, chn = tid & 3;
            const float* dp = det + ((yo2*64 + x)*4 + chn)*4;
            float s = dp[0] + dp[1] + dp[2] + dp[3];
            const int ygl = y0 + yo2;
            const int vg = (z*Hy + ygl)*Wx + x;
            if (chn == 0) {
                float logit = s + blog[0];
                float score = 1.f/(1.f + expf(-logit));
                unsigned sb = f2sort(score);
                keys[vg] = ((unsigned long long)sb << 32)
                         | (unsigned long long)(0xFFFFFFFFu - (unsigned)vg);
                atomicAdd(&hist[sb >> 16], 1u);
            } else {
                float coord = (chn == 1) ? (float)z : (chn == 2) ? (float)ygl : (float)x;
                float loc = (coord + 0.5f)*4.0f + (s + breg[chn-1])*4.0f;
                locs[(size_t)vg*3 + (chn-1)] = loc;
            }
        }
    }
}

// --------------------------- selection / NMS tail ---------------------------
// Parallel cut finder over 64K buckets: suffix sums via Hillis-Steele scan.
__global__ __launch_bounds__(1024) void find_cut_kernel(const unsigned* __restrict__ hist,
                                                        unsigned* __restrict__ cutp) {
    __shared__ unsigned ps[1024];
    __shared__ unsigned fs[64];
    __shared__ int sh_cb;
    __shared__ unsigned sh_acc;
    int t = threadIdx.x;
    unsigned s = 0;
    const unsigned* hp = hist + (size_t)t*64;
    for (int j = 0; j < 64; ++j) s += hp[j];
    ps[t] = s;
    __syncthreads();
    for (int off = 1; off < 1024; off <<= 1) {
        unsigned v = ps[t] + ((t + off < 1024) ? ps[t + off] : 0u);
        __syncthreads();
        ps[t] = v;
        __syncthreads();
    }
    // ps[t] = suffix count of buckets >= t*64 ; non-increasing, ps[0] = NVOX
    if (ps[t] >= TOPK && (t == 1023 || ps[t+1] < TOPK)) {
        sh_cb = t; sh_acc = (t == 1023) ? 0u : ps[t+1];
    }
    __syncthreads();
    int cb = sh_cb; unsigned acc = sh_acc;
    if (t < 64) {
        unsigned f = acc;
        for (int u = t; u < 64; ++u) f += hist[(size_t)cb*64 + u];
        fs[t] = f;
    }
    __syncthreads();
    if (t < 64) {
        if (fs[t] >= TOPK && (t == 63 || fs[t+1] < TOPK))
            cutp[0] = ((unsigned)(cb*64 + t)) << 16;
    }
}

__global__ void compact_kernel(const unsigned long long* __restrict__ keys,
                               const unsigned* __restrict__ cutp,
                               unsigned* __restrict__ counter,
                               unsigned long long* __restrict__ cand) {
    int i = blockIdx.x*blockDim.x + threadIdx.x;
    unsigned thr = cutp[0];
    unsigned long long k = keys[i];
    if ((unsigned)(k >> 32) >= thr) {
        unsigned p = atomicAdd(counter, 1u);
        if (p < CAND_CAP) cand[p] = k;
    }
}

// Rank sort (keys unique): scatter packed (z,y,x,score) by exact rank.
__global__ __launch_bounds__(128) void rank_kernel(const unsigned* __restrict__ counter,
        const unsigned long long* __restrict__ cand, const float* __restrict__ locs,
        float4* __restrict__ loc4G) {
    __shared__ unsigned long long kbuf[CAND_CAP];   // 32 KB
    int t = threadIdx.x;
    int g = blockIdx.x*128 + t;
    int M = (int)*counter; if (M > CAND_CAP) M = CAND_CAP;
    for (int i = t; i < CAND_CAP; i += 128) kbuf[i] = (i < M) ? cand[i] : 0ull;
    __syncthreads();
    if (g >= M) return;
    unsigned long long mykey = kbuf[g];
    int rank = 0;
    for (int j = 0; j < M; ++j) rank += (kbuf[j] > mykey) ? 1 : 0;
    if (rank < TOPK) {
        unsigned idx = 0xFFFFFFFFu - (unsigned)(mykey & 0xFFFFFFFFull);
        float4 v;
        v.x = locs[(size_t)idx*3 + 0];
        v.y = locs[(size_t)idx*3 + 1];
        v.z = locs[(size_t)idx*3 + 2];
        v.w = sort2f((unsigned)(mykey >> 32));
        loc4G[rank] = v;
    }
}

// Neighbor lists within NMS radius (candidates vs all, LDS broadcast scan).
__global__ __launch_bounds__(64) void nbr_kernel(const float4* __restrict__ loc4G,
        unsigned short* __restrict__ nbidx, unsigned char* __restrict__ nbcnt) {
    __shared__ float4 b4[TOPK];   // 32 KB
    int t = threadIdx.x;
    int g = blockIdx.x*64 + t;
    for (int i = t; i < TOPK; i += 64) b4[i] = loc4G[i];
    __syncthreads();
    float4 me = b4[g];
    int cnt = 0;
    for (int j = 0; j < TOPK; ++j) {
        float4 o = b4[j];
        float dz = o.x - me.x, dy = o.y - me.y, dx = o.z - me.z;
        float d2 = dz*dz + dy*dy + dx*dx;
        if (d2 < 64.0f && j != g) {
            if (cnt < NBCAP) nbidx[(size_t)g*NBCAP + cnt] = (unsigned short)j;
            cnt++;
        }
    }
    nbcnt[g] = (unsigned char)min(cnt, 255);
}

// Greedy NMS via neighbor lists, wave-synchronous serial chain, early
// termination at 256 keeps (later flags provably can't affect output).
__global__ __launch_bounds__(512) void nms_kernel(const float4* __restrict__ loc4G,
        const unsigned short* __restrict__ nbidx, const unsigned char* __restrict__ nbcnt,
        const int* __restrict__ mask, float* __restrict__ out) {
    __shared__ float4 p4[TOPK];                 // 32 KB
    __shared__ unsigned short snb[TOPK*NBCAP];  // 64 KB
    __shared__ unsigned char scnt[TOPK];
    __shared__ unsigned char supf[TOPK];
    __shared__ unsigned char keepB[TOPK];
    __shared__ unsigned keepw[64];
    __shared__ int wpre[64];
    __shared__ int sh_nk;
    int t = threadIdx.x;
    for (int i = t; i < TOPK; i += 512) {
        p4[i] = loc4G[i]; scnt[i] = nbcnt[i]; supf[i] = 0; keepB[i] = 0;
    }
    for (int i = t; i < TOPK*NBCAP/8; i += 512)
        ((uint4*)snb)[i] = ((const uint4*)nbidx)[i];
    __syncthreads();
    if (t < 64) {
        const int l = t;
        float cz[32], cy[32], cx[32];   // fallback cache (overflowed nbr lists)
        #pragma unroll
        for (int j = 0; j < 32; ++j) {
            float4 v = p4[l*32 + j];
            cz[j] = v.x; cy[j] = v.y; cx[j] = v.z;
        }
        int myok = 0;
        #pragma unroll
        for (int j = 0; j < 32; ++j) myok += (p4[l*32 + j].w >= 0.2f) ? 1 : 0;
        #pragma unroll
        for (int s = 1; s < 64; s <<= 1) myok += __shfl_xor(myok, s, 64);
        const int NS = myok;            // scores sorted desc -> prefix
        int keeps = 0;
        for (int i = 0; i < NS; ++i) {
            bool kept = (supf[i] == 0);
            if (kept) {
                if (l == 0) keepB[i] = 1;
                ++keeps;
                const int cnt = scnt[i];
                if (cnt <= NBCAP) {
                    if (l < cnt) supf[snb[i*NBCAP + l]] = 1;
                } else {
                    float4 pv = p4[i];
                    #pragma unroll
                    for (int j = 0; j < 32; ++j) {
                        float dz = cz[j]-pv.x, dy = cy[j]-pv.y, dx = cx[j]-pv.z;
                        if (dz*dz + dy*dy + dx*dx < 64.0f) supf[l*32 + j] = 1;
                    }
                }
                asm volatile("s_waitcnt lgkmcnt(0)" ::: "memory");
                if (keeps >= MAXOUT) break;
            }
        }
    }
    __syncthreads();
    if (t < 64) {
        unsigned wmask = 0u;
        for (int j = 0; j < 32; ++j) wmask |= (keepB[t*32 + j] ? 1u : 0u) << j;
        keepw[t] = wmask;
    }
    __syncthreads();
    if (t < 64) {
        int p = 0;
        for (int j = 0; j < t; ++j) p += __popc(keepw[j]);
        wpre[t] = p;
        if (t == 63) sh_nk = p + __popc(keepw[63]);
    }
    __syncthreads();
    const int nk = sh_nk;
    for (int i = t; i < TOPK; i += 512) {
        unsigned w = keepw[i >> 5];
        bool kp = (w >> (i & 31)) & 1u;
        int rk = wpre[i >> 5] + __popc(w & ((1u << (i & 31)) - 1u));
        int slot = kp ? rk : (nk + (i - rk));
        if (slot < MAXOUT) {
            float4 v = p4[i];
            float lz = v.x, ly = v.y, lx = v.z;
            float sc = kp ? v.w : 0.f;
            int iz = (int)floorf(lz), iy = (int)floorf(ly), ix = (int)floorf(lx);
            int cz2 = min(max(iz,0),Dz*4-1), cy2 = min(max(iy,0),Hy*4-1), cx2 = min(max(ix,0),Wx*4-1);
            bool inr = (iz==cz2) && (iy==cy2) && (ix==cx2);
            float osc = (inr && mask[((size_t)cz2*(Hy*4) + cy2)*(Wx*4) + cx2] != 0) ? sc : 0.f;
            out[slot*4+0] = lz; out[slot*4+1] = ly; out[slot*4+2] = lx; out[slot*4+3] = osc;
        }
    }
}

extern "C" void kernel_launch(void* const* d_in, const int* in_sizes, int n_in,
                              void* d_out, int out_size, void* d_ws, size_t ws_size,
                              hipStream_t stream) {
    const float* feature = (const float*)d_in[0];
    const int*   mask    = (const int*)d_in[1];
    const float* w0   = (const float*)d_in[2];
    const float* b0   = (const float*)d_in[3];
    const float* w1   = (const float*)d_in[4];
    const float* b1   = (const float*)d_in[5];
    const float* wlog = (const float*)d_in[6];
    const float* blog = (const float*)d_in[7];
    const float* wreg = (const float*)d_in[8];
    const float* breg = (const float*)d_in[9];

    char* ws = (char*)d_ws;
    size_t off = 0;
    unsigned short* h1hi = (unsigned short*)(ws + off); off += (size_t)NVOX*CHN*2;  // 33.5 MB
    unsigned short* h1lo = (unsigned short*)(ws + off); off += (size_t)NVOX*CHN*2;  // 33.5 MB
    u16x8* wpk0 = (u16x8*)(ws + off);               off += (size_t)442368*16;       // 7.1 MB
    u16x8* wpk1 = (u16x8*)(ws + off);               off += (size_t)442368*16;       // 7.1 MB
    unsigned long long* keys = (unsigned long long*)(ws + off); off += (size_t)NVOX*8;
    float* locs = (float*)(ws + off);               off += (size_t)NVOX*3*4;
    unsigned* hist = (unsigned*)(ws + off);         off += (size_t)NHIST*4;         // 256 KB
    unsigned* counter = (unsigned*)(ws + off);      off += 256;
    unsigned* cutp = counter + 1;
    float4* zerob = (float4*)(ws + off);            off += 256;
    unsigned long long* cand = (unsigned long long*)(ws + off); off += (size_t)CAND_CAP*8;
    float4* loc4G = (float4*)(ws + off);            off += (size_t)TOPK*16;
    unsigned short* nbidx = (unsigned short*)(ws + off); off += (size_t)TOPK*NBCAP*2;
    unsigned char* nbcnt = (unsigned char*)(ws + off);   off += (size_t)TOPK;
    if (ws_size < off) return;   // scratch too small: fail loudly (poison output)

    prep_kernel<<<1792, 256, 0, stream>>>(w0, w1, wpk0, wpk1, hist, counter, zerob);
    dim3 cgrid(Hy/2, Dz);
    conv_kernel<0><<<cgrid, 512, 0, stream>>>(feature, nullptr, nullptr, wpk0, b0,
                                              zerob, h1hi, h1lo,
                                              nullptr, nullptr, nullptr, nullptr,
                                              nullptr, nullptr, nullptr);
    conv_kernel<1><<<cgrid, 512, 0, stream>>>(nullptr, h1hi, h1lo, wpk1, b1,
                                              zerob, nullptr, nullptr,
                                              wlog, blog, wreg, breg,
                                              locs, keys, hist);
    find_cut_kernel<<<1, 1024, 0, stream>>>(hist, cutp);
    compact_kernel<<<NVOX/256, 256, 0, stream>>>(keys, cutp, counter, cand);
    rank_kernel<<<CAND_CAP/128, 128, 0, stream>>>(counter, cand, locs, loc4G);
    nbr_kernel<<<TOPK/64, 64, 0, stream>>>(loc4G, nbidx, nbcnt);
    nms_kernel<<<1, 512, 0, stream>>>(loc4G, nbidx, nbcnt, mask, (float*)d_out);
}

// Round 6
// 1381.893 us; speedup vs baseline: 1.1288x; 1.1288x over previous
//
#include <hip/hip_runtime.h>
#include <math.h>

#define Dz 16
#define Hy 64
#define Wx 64
#define CHN 256
#define NVOX (Dz*Hy*Wx)      // 65536
#define TOPK 2048
#define MAXOUT 256
#define CAND_CAP 4096
#define NBCAP 16
#define NHIST 65536

typedef __attribute__((ext_vector_type(8))) _Float16 h8;
typedef __attribute__((ext_vector_type(8))) unsigned short u16x8;
typedef __attribute__((ext_vector_type(4))) float f32x4;

__device__ __forceinline__ float gelu_tanh(float x) {
    return 0.5f*x*(1.0f + tanhf(0.7978845608028654f*(x + 0.044715f*x*x*x)));
}
__device__ __forceinline__ unsigned f2sort(float f) {
    unsigned u = __float_as_uint(f);
    return (u & 0x80000000u) ? ~u : (u | 0x80000000u);
}
__device__ __forceinline__ float sort2f(unsigned s) {
    unsigned u = (s & 0x80000000u) ? (s & 0x7fffffffu) : ~s;
    return __uint_as_float(u);
}

#define MFMA(d, a, b) d = __builtin_amdgcn_mfma_f32_16x16x32_f16(a, b, d, 0, 0, 0)

// ---------------------------------------------------------------------------
// prep: pack weights (f32 -> per-lane MFMA B-fragment f16 hi/lo, layout
// chunk = (((tap*8+kbg)*16+ng)*2+plane)*64 + lane) + zero hist/counter.
// ---------------------------------------------------------------------------
__global__ __launch_bounds__(256) void prep_kernel(const float* __restrict__ w0,
        const float* __restrict__ w1, u16x8* __restrict__ wpk0,
        u16x8* __restrict__ wpk1, unsigned* __restrict__ hist,
        unsigned* __restrict__ counter) {
    int b = blockIdx.x, t = threadIdx.x;
    if (b < 1728) {
        int id = b*256 + t;                       // 442368 total
        int l = (id >= 221184) ? 1 : 0;
        int r = id - l*221184;
        int lane = r & 63, ng = (r >> 6) & 15, kbg = (r >> 10) & 7, tp = r >> 13;
        const float* w = l ? w1 : w0;
        u16x8* dst = l ? wpk1 : wpk0;
        h8 hv, lv;
        #pragma unroll
        for (int j = 0; j < 8; ++j) {
            int k = kbg*32 + (lane >> 4)*8 + j;
            int co = ng*16 + (lane & 15);
            float v = w[((size_t)tp*CHN + k)*CHN + co];
            _Float16 h = (_Float16)v;
            hv[j] = h;
            lv[j] = (_Float16)(v - (float)h);
        }
        size_t base = (((size_t)(tp*8 + kbg)*16 + ng)*2)*64 + lane;
        dst[base]      = __builtin_bit_cast(u16x8, hv);
        dst[base + 64] = __builtin_bit_cast(u16x8, lv);
    } else {
        int zb = b - 1728;                        // 0..63
        int i = zb*256 + t;                       // 0..16383
        hist[i] = 0u; hist[i + 16384] = 0u; hist[i + 32768] = 0u; hist[i + 49152] = 0u;
        if (zb == 0 && t == 0) counter[0] = 0u;
    }
}

// ---------------------------------------------------------------------------
// Conv layer as MFMA GEMM (reg-staged; gl_lds empirically regressed: 2x FETCH
// + 54x LDS conflicts on this halo pattern). Block = (z, y0..y0+1): M=128
// voxels, N=256 cos. 512 threads = 8 waves: yo = w>>2, wn = w&3.
// LDS: [plane2][iy4][row66][chunk8] of 16B f16 chunks, XOR-(r&7) swizzled.
// ---------------------------------------------------------------------------
template<int LAYER>
__global__ __launch_bounds__(512, 4) void conv_kernel(
        const float* __restrict__ fsrc,
        const unsigned short* __restrict__ hhi, const unsigned short* __restrict__ hlo,
        const u16x8* __restrict__ wpk, const float* __restrict__ bias,
        unsigned short* __restrict__ ohi, unsigned short* __restrict__ olo,
        const float* __restrict__ wlog, const float* __restrict__ blog,
        const float* __restrict__ wreg, const float* __restrict__ breg,
        float* __restrict__ locs, unsigned long long* __restrict__ keys,
        unsigned* __restrict__ hist) {
    __shared__ h8 sm[4224];                       // 67584 B
    const int tid = threadIdx.x;
    const int lane = tid & 63, w = tid >> 6;
    const int yo = w >> 2, wn = w & 3;
    const int lr = lane & 15, lg = lane >> 4;
    const int z = blockIdx.y, y0 = blockIdx.x*2;

    f32x4 acc[4][4];
    #pragma unroll
    for (int m = 0; m < 4; ++m)
        #pragma unroll
        for (int n = 0; n < 4; ++n) acc[m][n] = (f32x4){0.f,0.f,0.f,0.f};

    for (int dz = 0; dz < 3; ++dz) {
        const int zz = z + dz - 1;
        for (int kc = 0; kc < 4; ++kc) {
            __syncthreads();   // protect LDS from previous phase's readers
            // ------------- stage 4 in-rows (hi/lo) for this (dz, kc) -------------
            if (LAYER == 0) {
                for (int cidx = tid; cidx < 2112; cidx += 512) {
                    int cd = cidx & 7;
                    int rr = cidx >> 3;
                    int r = rr % 66, iy = rr / 66;
                    int ygl = y0 - 1 + iy, xin = r - 1;
                    h8 hv = {0,0,0,0,0,0,0,0}, lv = {0,0,0,0,0,0,0,0};
                    if (((unsigned)zz < (unsigned)Dz) & ((unsigned)ygl < (unsigned)Hy)
                        & ((unsigned)xin < (unsigned)Wx)) {
                        const float* s = fsrc + ((size_t)((zz*Hy + ygl)*Wx + xin))*CHN
                                              + kc*64 + cd*8;
                        float4 t0 = *(const float4*)s;
                        float4 t1 = *(const float4*)(s + 4);
                        float vv[8] = {t0.x,t0.y,t0.z,t0.w,t1.x,t1.y,t1.z,t1.w};
                        #pragma unroll
                        for (int j = 0; j < 8; ++j) {
                            _Float16 h = (_Float16)vv[j];
                            hv[j] = h;
                            lv[j] = (_Float16)(vv[j] - (float)h);
                        }
                    }
                    int sl = cd ^ (r & 7);
                    sm[(iy*66 + r)*8 + sl] = hv;
                    sm[2112 + (iy*66 + r)*8 + sl] = lv;
                }
            } else {
                for (int cidx = tid; cidx < 4224; cidx += 512) {
                    int c = cidx & 7;
                    int rr = cidx >> 3;
                    int r = rr % 66, tt = rr / 66;     // tt = p*4+iy
                    int p = tt >> 2, iy = tt & 3;
                    int ygl = y0 - 1 + iy, xin = r - 1;
                    u16x8 v = {0,0,0,0,0,0,0,0};
                    if (((unsigned)zz < (unsigned)Dz) & ((unsigned)ygl < (unsigned)Hy)
                        & ((unsigned)xin < (unsigned)Wx)) {
                        const unsigned short* bp = p ? hlo : hhi;
                        v = *(const u16x8*)(bp + ((size_t)((zz*Hy + ygl)*Wx + xin))*CHN
                                               + kc*64 + (size_t)((c ^ (r & 7)))*8);
                    }
                    sm[cidx] = __builtin_bit_cast(h8, v);
                }
            }
            __syncthreads();
            // ------------- compute: 9 (dy,dx) taps x 2 kb -------------
            for (int dy = 0; dy < 3; ++dy) {
                const int iyA = yo + dy;
                const h8* As = sm + iyA*528;
                #pragma unroll
                for (int dx = 0; dx < 3; ++dx) {
                    const int tap = (dz*3 + dy)*3 + dx;
                    #pragma unroll
                    for (int kb = 0; kb < 2; ++kb) {
                        const int kbg = kc*2 + kb;
                        const u16x8* wb = wpk + ((size_t)(tap*8 + kbg)*32 + wn*8)*64 + lane;
                        h8 bh[4];
                        #pragma unroll
                        for (int n = 0; n < 4; ++n)
                            bh[n] = __builtin_bit_cast(h8, wb[(size_t)n*128]);
                        #pragma unroll
                        for (int m = 0; m < 4; ++m) {
                            const int r = m*16 + lr + dx;
                            const int sl = (kb*4 + lg) ^ (r & 7);
                            h8 ah = As[r*8 + sl];
                            h8 al = As[2112 + r*8 + sl];
                            #pragma unroll
                            for (int n = 0; n < 4; ++n) {
                                MFMA(acc[m][n], ah, bh[n]);
                                MFMA(acc[m][n], al, bh[n]);
                            }
                        }
                        h8 bl[4];
                        #pragma unroll
                        for (int n = 0; n < 4; ++n)
                            bl[n] = __builtin_bit_cast(h8, wb[(size_t)n*128 + 64]);
                        #pragma unroll
                        for (int m = 0; m < 4; ++m) {
                            const int r = m*16 + lr + dx;
                            const int sl = (kb*4 + lg) ^ (r & 7);
                            h8 ah = As[r*8 + sl];
                            #pragma unroll
                            for (int n = 0; n < 4; ++n) MFMA(acc[m][n], ah, bl[n]);
                        }
                    }
                }
            }
        }
    }

    // ------------------------------ epilogue ------------------------------
    float bn[4];
    #pragma unroll
    for (int n = 0; n < 4; ++n) bn[n] = bias[wn*64 + n*16 + lr];

    if (LAYER == 0) {
        const int ygl = y0 + yo;
        #pragma unroll
        for (int m = 0; m < 4; ++m) {
            #pragma unroll
            for (int rg = 0; rg < 4; ++rg) {
                const int x = m*16 + lg*4 + rg;
                const size_t vbase = ((size_t)((z*Hy + ygl)*Wx + x))*CHN;
                #pragma unroll
                for (int n = 0; n < 4; ++n) {
                    const int co = wn*64 + n*16 + lr;
                    float g = gelu_tanh(acc[m][n][rg] + bn[n]);
                    _Float16 h = (_Float16)g;
                    _Float16 l = (_Float16)(g - (float)h);
                    ohi[vbase + co] = __builtin_bit_cast(unsigned short, h);
                    olo[vbase + co] = __builtin_bit_cast(unsigned short, l);
                }
            }
        }
    } else {
        // detection head from registers: per-lane partial dots over its 4 cos
        float wl[4], wr0[4], wr1[4], wr2[4];
        #pragma unroll
        for (int n = 0; n < 4; ++n) {
            const int co = wn*64 + n*16 + lr;
            wl[n] = wlog[co];
            wr0[n] = wreg[co*3 + 0]; wr1[n] = wreg[co*3 + 1]; wr2[n] = wreg[co*3 + 2];
        }
        float p[4][16];
        #pragma unroll
        for (int c = 0; c < 4; ++c)
            #pragma unroll
            for (int xi = 0; xi < 16; ++xi) p[c][xi] = 0.f;
        #pragma unroll
        for (int m = 0; m < 4; ++m)
            #pragma unroll
            for (int rg = 0; rg < 4; ++rg) {
                const int xi = m*4 + rg;
                #pragma unroll
                for (int n = 0; n < 4; ++n) {
                    float g = gelu_tanh(acc[m][n][rg] + bn[n]);
                    p[0][xi] += g*wl[n];
                    p[1][xi] += g*wr0[n];
                    p[2][xi] += g*wr1[n];
                    p[3][xi] += g*wr2[n];
                }
            }
        #pragma unroll
        for (int st = 0; st < 4; ++st) {
            const int s = 1 << st;
            #pragma unroll
            for (int c = 0; c < 4; ++c)
                #pragma unroll
                for (int xi = 0; xi < 16; ++xi)
                    p[c][xi] += __shfl_xor(p[c][xi], s, 64);
        }
        __syncthreads();                 // stage buffer dead -> reuse as det
        float* det = (float*)sm;         // [2][64][4][4] = 8 KB
        if (lr == 0) {
            #pragma unroll
            for (int m = 0; m < 4; ++m)
                #pragma unroll
                for (int rg = 0; rg < 4; ++rg) {
                    const int x = m*16 + lg*4 + rg;
                    #pragma unroll
                    for (int c = 0; c < 4; ++c)
                        det[((yo*64 + x)*4 + c)*4 + wn] = p[c][m*4 + rg];
                }
        }
        __syncthreads();
        {
            const int yo2 = tid >> 8, x = (tid >> 2) & 63, chn = tid & 3;
            const float* dp = det + ((yo2*64 + x)*4 + chn)*4;
            float s = dp[0] + dp[1] + dp[2] + dp[3];
            const int ygl = y0 + yo2;
            const int vg = (z*Hy + ygl)*Wx + x;
            if (chn == 0) {
                float logit = s + blog[0];
                float score = 1.f/(1.f + expf(-logit));
                unsigned sb = f2sort(score);
                keys[vg] = ((unsigned long long)sb << 32)
                         | (unsigned long long)(0xFFFFFFFFu - (unsigned)vg);
                atomicAdd(&hist[sb >> 16], 1u);
            } else {
                float coord = (chn == 1) ? (float)z : (chn == 2) ? (float)ygl : (float)x;
                float loc = (coord + 0.5f)*4.0f + (s + breg[chn-1])*4.0f;
                locs[(size_t)vg*3 + (chn-1)] = loc;
            }
        }
    }
}

// --------------------------- selection / NMS tail ---------------------------
// Parallel cut finder over 64K buckets: suffix sums via Hillis-Steele scan.
__global__ __launch_bounds__(1024) void find_cut_kernel(const unsigned* __restrict__ hist,
                                                        unsigned* __restrict__ cutp) {
    __shared__ unsigned ps[1024];
    __shared__ unsigned fs[64];
    __shared__ int sh_cb;
    __shared__ unsigned sh_acc;
    int t = threadIdx.x;
    unsigned s = 0;
    const unsigned* hp = hist + (size_t)t*64;
    for (int j = 0; j < 64; ++j) s += hp[j];
    ps[t] = s;
    __syncthreads();
    for (int off = 1; off < 1024; off <<= 1) {
        unsigned v = ps[t] + ((t + off < 1024) ? ps[t + off] : 0u);
        __syncthreads();
        ps[t] = v;
        __syncthreads();
    }
    // ps[t] = suffix count of buckets >= t*64 ; non-increasing, ps[0] = NVOX
    if (ps[t] >= TOPK && (t == 1023 || ps[t+1] < TOPK)) {
        sh_cb = t; sh_acc = (t == 1023) ? 0u : ps[t+1];
    }
    __syncthreads();
    int cb = sh_cb; unsigned acc = sh_acc;
    if (t < 64) {
        unsigned f = acc;
        for (int u = t; u < 64; ++u) f += hist[(size_t)cb*64 + u];
        fs[t] = f;
    }
    __syncthreads();
    if (t < 64) {
        if (fs[t] >= TOPK && (t == 63 || fs[t+1] < TOPK))
            cutp[0] = ((unsigned)(cb*64 + t)) << 16;
    }
}

__global__ void compact_kernel(const unsigned long long* __restrict__ keys,
                               const unsigned* __restrict__ cutp,
                               unsigned* __restrict__ counter,
                               unsigned long long* __restrict__ cand) {
    int i = blockIdx.x*blockDim.x + threadIdx.x;
    unsigned thr = cutp[0];
    unsigned long long k = keys[i];
    if ((unsigned)(k >> 32) >= thr) {
        unsigned p = atomicAdd(counter, 1u);
        if (p < CAND_CAP) cand[p] = k;
    }
}

// Rank sort (keys unique): scatter packed (z,y,x,score) by exact rank.
__global__ __launch_bounds__(128) void rank_kernel(const unsigned* __restrict__ counter,
        const unsigned long long* __restrict__ cand, const float* __restrict__ locs,
        float4* __restrict__ loc4G) {
    __shared__ unsigned long long kbuf[CAND_CAP];   // 32 KB
    int t = threadIdx.x;
    int g = blockIdx.x*128 + t;
    int M = (int)*counter; if (M > CAND_CAP) M = CAND_CAP;
    for (int i = t; i < CAND_CAP; i += 128) kbuf[i] = (i < M) ? cand[i] : 0ull;
    __syncthreads();
    if (g >= M) return;
    unsigned long long mykey = kbuf[g];
    int rank = 0;
    for (int j = 0; j < M; ++j) rank += (kbuf[j] > mykey) ? 1 : 0;
    if (rank < TOPK) {
        unsigned idx = 0xFFFFFFFFu - (unsigned)(mykey & 0xFFFFFFFFull);
        float4 v;
        v.x = locs[(size_t)idx*3 + 0];
        v.y = locs[(size_t)idx*3 + 1];
        v.z = locs[(size_t)idx*3 + 2];
        v.w = sort2f((unsigned)(mykey >> 32));
        loc4G[rank] = v;
    }
}

// Neighbor lists within NMS radius (candidates vs all, LDS broadcast scan).
__global__ __launch_bounds__(64) void nbr_kernel(const float4* __restrict__ loc4G,
        unsigned short* __restrict__ nbidx, unsigned char* __restrict__ nbcnt) {
    __shared__ float4 b4[TOPK];   // 32 KB
    int t = threadIdx.x;
    int g = blockIdx.x*64 + t;
    for (int i = t; i < TOPK; i += 64) b4[i] = loc4G[i];
    __syncthreads();
    float4 me = b4[g];
    int cnt = 0;
    for (int j = 0; j < TOPK; ++j) {
        float4 o = b4[j];
        float dz = o.x - me.x, dy = o.y - me.y, dx = o.z - me.z;
        float d2 = dz*dz + dy*dy + dx*dx;
        if (d2 < 64.0f && j != g) {
            if (cnt < NBCAP) nbidx[(size_t)g*NBCAP + cnt] = (unsigned short)j;
            cnt++;
        }
    }
    nbcnt[g] = (unsigned char)min(cnt, 255);
}

// Greedy NMS via neighbor lists, wave-synchronous serial chain, early
// termination at 256 keeps (later flags provably can't affect output).
__global__ __launch_bounds__(512) void nms_kernel(const float4* __restrict__ loc4G,
        const unsigned short* __restrict__ nbidx, const unsigned char* __restrict__ nbcnt,
        const int* __restrict__ mask, float* __restrict__ out) {
    __shared__ float4 p4[TOPK];                 // 32 KB
    __shared__ unsigned short snb[TOPK*NBCAP];  // 64 KB
    __shared__ unsigned char scnt[TOPK];
    __shared__ unsigned char supf[TOPK];
    __shared__ unsigned char keepB[TOPK];
    __shared__ unsigned keepw[64];
    __shared__ int wpre[64];
    __shared__ int sh_nk;
    int t = threadIdx.x;
    for (int i = t; i < TOPK; i += 512) {
        p4[i] = loc4G[i]; scnt[i] = nbcnt[i]; supf[i] = 0; keepB[i] = 0;
    }
    for (int i = t; i < TOPK*NBCAP/8; i += 512)
        ((uint4*)snb)[i] = ((const uint4*)nbidx)[i];
    __syncthreads();
    if (t < 64) {
        const int l = t;
        float cz[32], cy[32], cx[32];   // fallback cache (overflowed nbr lists)
        #pragma unroll
        for (int j = 0; j < 32; ++j) {
            float4 v = p4[l*32 + j];
            cz[j] = v.x; cy[j] = v.y; cx[j] = v.z;
        }
        int myok = 0;
        #pragma unroll
        for (int j = 0; j < 32; ++j) myok += (p4[l*32 + j].w >= 0.2f) ? 1 : 0;
        #pragma unroll
        for (int s = 1; s < 64; s <<= 1) myok += __shfl_xor(myok, s, 64);
        const int NS = myok;            // scores sorted desc -> prefix
        int keeps = 0;
        for (int i = 0; i < NS; ++i) {
            bool kept = (supf[i] == 0);
            if (kept) {
                if (l == 0) keepB[i] = 1;
                ++keeps;
                const int cnt = scnt[i];
                if (cnt <= NBCAP) {
                    if (l < cnt) supf[snb[i*NBCAP + l]] = 1;
                } else {
                    float4 pv = p4[i];
                    #pragma unroll
                    for (int j = 0; j < 32; ++j) {
                        float dz = cz[j]-pv.x, dy = cy[j]-pv.y, dx = cx[j]-pv.z;
                        if (dz*dz + dy*dy + dx*dx < 64.0f) supf[l*32 + j] = 1;
                    }
                }
                asm volatile("s_waitcnt lgkmcnt(0)" ::: "memory");
                if (keeps >= MAXOUT) break;
            }
        }
    }
    __syncthreads();
    if (t < 64) {
        unsigned wmask = 0u;
        for (int j = 0; j < 32; ++j) wmask |= (keepB[t*32 + j] ? 1u : 0u) << j;
        keepw[t] = wmask;
    }
    __syncthreads();
    if (t < 64) {
        int p = 0;
        for (int j = 0; j < t; ++j) p += __popc(keepw[j]);
        wpre[t] = p;
        if (t == 63) sh_nk = p + __popc(keepw[63]);
    }
    __syncthreads();
    const int nk = sh_nk;
    for (int i = t; i < TOPK; i += 512) {
        unsigned w = keepw[i >> 5];
        bool kp = (w >> (i & 31)) & 1u;
        int rk = wpre[i >> 5] + __popc(w & ((1u << (i & 31)) - 1u));
        int slot = kp ? rk : (nk + (i - rk));
        if (slot < MAXOUT) {
            float4 v = p4[i];
            float lz = v.x, ly = v.y, lx = v.z;
            float sc = kp ? v.w : 0.f;
            int iz = (int)floorf(lz), iy = (int)floorf(ly), ix = (int)floorf(lx);
            int cz2 = min(max(iz,0),Dz*4-1), cy2 = min(max(iy,0),Hy*4-1), cx2 = min(max(ix,0),Wx*4-1);
            bool inr = (iz==cz2) && (iy==cy2) && (ix==cx2);
            float osc = (inr && mask[((size_t)cz2*(Hy*4) + cy2)*(Wx*4) + cx2] != 0) ? sc : 0.f;
            out[slot*4+0] = lz; out[slot*4+1] = ly; out[slot*4+2] = lx; out[slot*4+3] = osc;
        }
    }
}

extern "C" void kernel_launch(void* const* d_in, const int* in_sizes, int n_in,
                              void* d_out, int out_size, void* d_ws, size_t ws_size,
                              hipStream_t stream) {
    const float* feature = (const float*)d_in[0];
    const int*   mask    = (const int*)d_in[1];
    const float* w0   = (const float*)d_in[2];
    const float* b0   = (const float*)d_in[3];
    const float* w1   = (const float*)d_in[4];
    const float* b1   = (const float*)d_in[5];
    const float* wlog = (const float*)d_in[6];
    const float* blog = (const float*)d_in[7];
    const float* wreg = (const float*)d_in[8];
    const float* breg = (const float*)d_in[9];

    char* ws = (char*)d_ws;
    size_t off = 0;
    unsigned short* h1hi = (unsigned short*)(ws + off); off += (size_t)NVOX*CHN*2;  // 33.5 MB
    unsigned short* h1lo = (unsigned short*)(ws + off); off += (size_t)NVOX*CHN*2;  // 33.5 MB
    u16x8* wpk0 = (u16x8*)(ws + off);               off += (size_t)442368*16;       // 7.1 MB
    u16x8* wpk1 = (u16x8*)(ws + off);               off += (size_t)442368*16;       // 7.1 MB
    unsigned long long* keys = (unsigned long long*)(ws + off); off += (size_t)NVOX*8;
    float* locs = (float*)(ws + off);               off += (size_t)NVOX*3*4;
    unsigned* hist = (unsigned*)(ws + off);         off += (size_t)NHIST*4;         // 256 KB
    unsigned* counter = (unsigned*)(ws + off);      off += 256;
    unsigned* cutp = counter + 1;
    unsigned long long* cand = (unsigned long long*)(ws + off); off += (size_t)CAND_CAP*8;
    float4* loc4G = (float4*)(ws + off);            off += (size_t)TOPK*16;
    unsigned short* nbidx = (unsigned short*)(ws + off); off += (size_t)TOPK*NBCAP*2;
    unsigned char* nbcnt = (unsigned char*)(ws + off);   off += (size_t)TOPK;
    if (ws_size < off) return;   // scratch too small: fail loudly (poison output)

    prep_kernel<<<1792, 256, 0, stream>>>(w0, w1, wpk0, wpk1, hist, counter);
    dim3 cgrid(Hy/2, Dz);
    conv_kernel<0><<<cgrid, 512, 0, stream>>>(feature, nullptr, nullptr, wpk0, b0,
                                              h1hi, h1lo,
                                              nullptr, nullptr, nullptr, nullptr,
                                              nullptr, nullptr, nullptr);
    conv_kernel<1><<<cgrid, 512, 0, stream>>>(nullptr, h1hi, h1lo, wpk1, b1,
                                              nullptr, nullptr,
                                              wlog, blog, wreg, breg,
                                              locs, keys, hist);
    find_cut_kernel<<<1, 1024, 0, stream>>>(hist, cutp);
    compact_kernel<<<NVOX/256, 256, 0, stream>>>(keys, cutp, counter, cand);
    rank_kernel<<<CAND_CAP/128, 128, 0, stream>>>(counter, cand, locs, loc4G);
    nbr_kernel<<<TOPK/64, 64, 0, stream>>>(loc4G, nbidx, nbcnt);
    nms_kernel<<<1, 512, 0, stream>>>(loc4G, nbidx, nbcnt, mask, (float*)d_out);
}

// Round 7
// 1371.778 us; speedup vs baseline: 1.1371x; 1.0074x over previous
//
#include <hip/hip_runtime.h>
#include <math.h>

#define Dz 16
#define Hy 64
#define Wx 64
#define CHN 256
#define NVOX (Dz*Hy*Wx)      // 65536
#define TOPK 2048
#define MAXOUT 256
#define CAND_CAP 4096
#define NBCAP 16
#define NHIST 65536

typedef __attribute__((ext_vector_type(8))) _Float16 h8;
typedef __attribute__((ext_vector_type(8))) unsigned short u16x8;
typedef __attribute__((ext_vector_type(4))) float f32x4;

__device__ __forceinline__ float gelu_tanh(float x) {
    return 0.5f*x*(1.0f + tanhf(0.7978845608028654f*(x + 0.044715f*x*x*x)));
}
__device__ __forceinline__ unsigned f2sort(float f) {
    unsigned u = __float_as_uint(f);
    return (u & 0x80000000u) ? ~u : (u | 0x80000000u);
}
__device__ __forceinline__ float sort2f(unsigned s) {
    unsigned u = (s & 0x80000000u) ? (s & 0x7fffffffu) : ~s;
    return __uint_as_float(u);
}

#define MFMA(d, a, b) d = __builtin_amdgcn_mfma_f32_16x16x32_f16(a, b, d, 0, 0, 0)

// ---------------------------------------------------------------------------
// prep: pack weights (f32 -> per-lane MFMA B-fragment f16 hi/lo, layout
// chunk = (((tap*8+kbg)*16+ng)*2+plane)*64 + lane) + zero hist/counter.
// ---------------------------------------------------------------------------
__global__ __launch_bounds__(256) void prep_kernel(const float* __restrict__ w0,
        const float* __restrict__ w1, u16x8* __restrict__ wpk0,
        u16x8* __restrict__ wpk1, unsigned* __restrict__ hist,
        unsigned* __restrict__ counter) {
    int b = blockIdx.x, t = threadIdx.x;
    if (b < 1728) {
        int id = b*256 + t;                       // 442368 total
        int l = (id >= 221184) ? 1 : 0;
        int r = id - l*221184;
        int lane = r & 63, ng = (r >> 6) & 15, kbg = (r >> 10) & 7, tp = r >> 13;
        const float* w = l ? w1 : w0;
        u16x8* dst = l ? wpk1 : wpk0;
        h8 hv, lv;
        #pragma unroll
        for (int j = 0; j < 8; ++j) {
            int k = kbg*32 + (lane >> 4)*8 + j;
            int co = ng*16 + (lane & 15);
            float v = w[((size_t)tp*CHN + k)*CHN + co];
            _Float16 h = (_Float16)v;
            hv[j] = h;
            lv[j] = (_Float16)(v - (float)h);
        }
        size_t base = (((size_t)(tp*8 + kbg)*16 + ng)*2)*64 + lane;
        dst[base]      = __builtin_bit_cast(u16x8, hv);
        dst[base + 64] = __builtin_bit_cast(u16x8, lv);
    } else {
        int zb = b - 1728;                        // 0..63
        int i = zb*256 + t;                       // 0..16383
        hist[i] = 0u; hist[i + 16384] = 0u; hist[i + 32768] = 0u; hist[i + 49152] = 0u;
        if (zb == 0 && t == 0) counter[0] = 0u;
    }
}

// ---------------------------------------------------------------------------
// Stage helpers (reg-staged async pipeline).
// LDS tile per phase: [plane2][iy4][row66][slot8] of 16B f16 chunks.
// LAYER1: LDS linear in cidx, swizzle on SOURCE chunk (c ^ (r&7)).
// LAYER0: raw f32 loaded to regs; RNE hi/lo split at write; swizzle on DEST.
// Both produce byte-identical LDS contents to rounds 4/6.
// ---------------------------------------------------------------------------
__device__ __forceinline__ u16x8 ld1(int cidx, const unsigned short* __restrict__ hhi,
        const unsigned short* __restrict__ hlo, int zz, bool zok, int y0, int kc) {
    int c = cidx & 7, rr = cidx >> 3;
    int r = rr % 66, tt = rr / 66;
    int p = tt >> 2, iy = tt & 3;
    int ygl = y0 - 1 + iy, xin = r - 1;
    u16x8 v = {0,0,0,0,0,0,0,0};
    if (zok & ((unsigned)ygl < (unsigned)Hy) & ((unsigned)xin < (unsigned)Wx)) {
        const unsigned short* bp = p ? hlo : hhi;
        v = *(const u16x8*)(bp + ((size_t)((zz*Hy + ygl)*Wx + xin))*CHN
                            + kc*64 + (size_t)(c ^ (r & 7))*8);
    }
    return v;
}
__device__ __forceinline__ void ld0(int cidx, const float* __restrict__ fsrc,
        int zz, bool zok, int y0, int kc, float4& va, float4& vb) {
    int cd = cidx & 7, rr = cidx >> 3;
    int r = rr % 66, iy = rr / 66;
    int ygl = y0 - 1 + iy, xin = r - 1;
    va = make_float4(0.f,0.f,0.f,0.f); vb = va;
    if (zok & ((unsigned)ygl < (unsigned)Hy) & ((unsigned)xin < (unsigned)Wx)) {
        const float* s = fsrc + ((size_t)((zz*Hy + ygl)*Wx + xin))*CHN + kc*64 + cd*8;
        va = *(const float4*)s;
        vb = *(const float4*)(s + 4);
    }
}
__device__ __forceinline__ void st0(h8* __restrict__ dst, int cidx,
                                    float4 va, float4 vb) {
    int cd = cidx & 7, rr = cidx >> 3;
    int r = rr % 66, iy = rr / 66;
    float vv[8] = {va.x,va.y,va.z,va.w,vb.x,vb.y,vb.z,vb.w};
    h8 hv, lv;
    #pragma unroll
    for (int j = 0; j < 8; ++j) {
        _Float16 h = (_Float16)vv[j];
        hv[j] = h;
        lv[j] = (_Float16)(vv[j] - (float)h);
    }
    int sl = cd ^ (r & 7);
    dst[(iy*66 + r)*8 + sl] = hv;
    dst[2112 + (iy*66 + r)*8 + sl] = lv;
}

// ---------------------------------------------------------------------------
// Conv as MFMA GEMM, 1024 threads = 16 waves (mw 0..1 = output row, wn 0..7 =
// 32-co chunk), wave tile 64(M)x32(N), acc 4x2 f32x4 = 32 AGPR.
// Double-buffered LDS (2 x 67.5 KB); per phase: issue next loads -> compute ->
// ds_write -> ONE barrier. K-order & MFMA sequence identical to round 6.
// ---------------------------------------------------------------------------
template<int LAYER>
__global__ __launch_bounds__(1024) void conv_kernel(
        const float* __restrict__ fsrc,
        const unsigned short* __restrict__ hhi, const unsigned short* __restrict__ hlo,
        const u16x8* __restrict__ wpk, const float* __restrict__ bias,
        unsigned short* __restrict__ ohi, unsigned short* __restrict__ olo,
        const float* __restrict__ wlog, const float* __restrict__ blog,
        const float* __restrict__ wreg, const float* __restrict__ breg,
        float* __restrict__ locs, unsigned long long* __restrict__ keys,
        unsigned* __restrict__ hist) {
    __shared__ h8 sm[8448];                       // 135168 B (double buffer)
    const int tid = threadIdx.x;
    const int lane = tid & 63, w = tid >> 6;
    const int mw = w >> 3, wn = w & 7;
    const int lr = lane & 15, lg = lane >> 4;
    const int z = blockIdx.y, y0 = blockIdx.x*2;

    f32x4 acc[4][2];
    #pragma unroll
    for (int m = 0; m < 4; ++m)
        #pragma unroll
        for (int n = 0; n < 2; ++n) acc[m][n] = (f32x4){0.f,0.f,0.f,0.f};

    // stage-hold registers (statically named; only one layer's set is used)
    u16x8 s1a, s1b, s1c, s1d, s1e;
    float4 s0a0, s0a1, s0b0, s0b1, s0c0, s0c1;

#define STAGE_LOAD(DZ2, KC2) do {                                              \
    const int zz2_ = z + (DZ2) - 1;                                            \
    const bool zok2_ = (unsigned)zz2_ < (unsigned)Dz;                          \
    if constexpr (LAYER == 0) {                                                \
        ld0(tid,        fsrc, zz2_, zok2_, y0, (KC2), s0a0, s0a1);             \
        ld0(1024 + tid, fsrc, zz2_, zok2_, y0, (KC2), s0b0, s0b1);             \
        if (tid < 64) ld0(2048 + tid, fsrc, zz2_, zok2_, y0, (KC2), s0c0, s0c1);\
    } else {                                                                   \
        s1a = ld1(tid,        hhi, hlo, zz2_, zok2_, y0, (KC2));               \
        s1b = ld1(1024 + tid, hhi, hlo, zz2_, zok2_, y0, (KC2));               \
        s1c = ld1(2048 + tid, hhi, hlo, zz2_, zok2_, y0, (KC2));               \
        s1d = ld1(3072 + tid, hhi, hlo, zz2_, zok2_, y0, (KC2));               \
        if (tid < 128) s1e = ld1(4096 + tid, hhi, hlo, zz2_, zok2_, y0, (KC2));\
    }                                                                          \
    __builtin_amdgcn_sched_barrier(0);                                         \
} while (0)

#define STAGE_WRITE(PAR) do {                                                  \
    h8* dst_ = sm + (PAR)*4224;                                                \
    if constexpr (LAYER == 0) {                                                \
        st0(dst_, tid,        s0a0, s0a1);                                     \
        st0(dst_, 1024 + tid, s0b0, s0b1);                                     \
        if (tid < 64) st0(dst_, 2048 + tid, s0c0, s0c1);                       \
    } else {                                                                   \
        dst_[tid]        = __builtin_bit_cast(h8, s1a);                        \
        dst_[1024 + tid] = __builtin_bit_cast(h8, s1b);                        \
        dst_[2048 + tid] = __builtin_bit_cast(h8, s1c);                        \
        dst_[3072 + tid] = __builtin_bit_cast(h8, s1d);                        \
        if (tid < 128) dst_[4096 + tid] = __builtin_bit_cast(h8, s1e);         \
    }                                                                          \
} while (0)

    // prologue: stage phase 0 (dz=0, kc=0)
    STAGE_LOAD(0, 0);
    STAGE_WRITE(0);
    __syncthreads();

    for (int k = 0; k < 12; ++k) {
        const int dz = k >> 2, kc = k & 3;
        const int par = k & 1;
        if (k < 11) {
            const int k2 = k + 1;
            STAGE_LOAD(k2 >> 2, k2 & 3);
        }
        // ---------------- compute phase k: 9 taps x 2 kb ----------------
        const h8* As0 = sm + par*4224;
        for (int dy = 0; dy < 3; ++dy) {
            const int iyA = mw + dy;
            const h8* As = As0 + iyA*528;
            #pragma unroll
            for (int dx = 0; dx < 3; ++dx) {
                const int tap = (dz*3 + dy)*3 + dx;
                #pragma unroll
                for (int kb = 0; kb < 2; ++kb) {
                    const int kbg = kc*2 + kb;
                    const u16x8* wb = wpk + ((size_t)(tap*8 + kbg)*32 + wn*4)*64 + lane;
                    h8 bh0 = __builtin_bit_cast(h8, wb[0]);
                    h8 bh1 = __builtin_bit_cast(h8, wb[128]);
                    #pragma unroll
                    for (int m = 0; m < 4; ++m) {
                        const int r = m*16 + lr + dx;
                        const int sl = (kb*4 + lg) ^ (r & 7);
                        h8 ah = As[r*8 + sl];
                        h8 al = As[2112 + r*8 + sl];
                        MFMA(acc[m][0], ah, bh0);
                        MFMA(acc[m][0], al, bh0);
                        MFMA(acc[m][1], ah, bh1);
                        MFMA(acc[m][1], al, bh1);
                    }
                    h8 bl0 = __builtin_bit_cast(h8, wb[64]);
                    h8 bl1 = __builtin_bit_cast(h8, wb[192]);
                    #pragma unroll
                    for (int m = 0; m < 4; ++m) {
                        const int r = m*16 + lr + dx;
                        const int sl = (kb*4 + lg) ^ (r & 7);
                        h8 ah = As[r*8 + sl];
                        MFMA(acc[m][0], ah, bl0);
                        MFMA(acc[m][1], ah, bl1);
                    }
                }
            }
        }
        if (k < 11) {
            STAGE_WRITE((k + 1) & 1);
            __syncthreads();
        }
    }
#undef STAGE_LOAD
#undef STAGE_WRITE

    // ------------------------------ epilogue ------------------------------
    float bn[2];
    #pragma unroll
    for (int n = 0; n < 2; ++n) bn[n] = bias[wn*32 + n*16 + lr];

    if (LAYER == 0) {
        const int ygl = y0 + mw;
        #pragma unroll
        for (int m = 0; m < 4; ++m) {
            #pragma unroll
            for (int rg = 0; rg < 4; ++rg) {
                const int x = m*16 + lg*4 + rg;
                const size_t vbase = ((size_t)((z*Hy + ygl)*Wx + x))*CHN;
                #pragma unroll
                for (int n = 0; n < 2; ++n) {
                    const int co = wn*32 + n*16 + lr;
                    float g = gelu_tanh(acc[m][n][rg] + bn[n]);
                    _Float16 h = (_Float16)g;
                    _Float16 l = (_Float16)(g - (float)h);
                    ohi[vbase + co] = __builtin_bit_cast(unsigned short, h);
                    olo[vbase + co] = __builtin_bit_cast(unsigned short, l);
                }
            }
        }
    } else {
        // detection head: per-lane partial dots over this wave's 2 co-frags
        float wl[2], wr0[2], wr1[2], wr2[2];
        #pragma unroll
        for (int n = 0; n < 2; ++n) {
            const int co = wn*32 + n*16 + lr;
            wl[n] = wlog[co];
            wr0[n] = wreg[co*3 + 0]; wr1[n] = wreg[co*3 + 1]; wr2[n] = wreg[co*3 + 2];
        }
        float p[4][16];
        #pragma unroll
        for (int c = 0; c < 4; ++c)
            #pragma unroll
            for (int xi = 0; xi < 16; ++xi) p[c][xi] = 0.f;
        #pragma unroll
        for (int m = 0; m < 4; ++m)
            #pragma unroll
            for (int rg = 0; rg < 4; ++rg) {
                const int xi = m*4 + rg;
                #pragma unroll
                for (int n = 0; n < 2; ++n) {
                    float g = gelu_tanh(acc[m][n][rg] + bn[n]);
                    p[0][xi] += g*wl[n];
                    p[1][xi] += g*wr0[n];
                    p[2][xi] += g*wr1[n];
                    p[3][xi] += g*wr2[n];
                }
            }
        #pragma unroll
        for (int st = 0; st < 4; ++st) {
            const int s = 1 << st;
            #pragma unroll
            for (int c = 0; c < 4; ++c)
                #pragma unroll
                for (int xi = 0; xi < 16; ++xi)
                    p[c][xi] += __shfl_xor(p[c][xi], s, 64);
        }
        __syncthreads();                 // all compute done -> reuse sm as det
        float* det = (float*)sm;         // [128 vox][4 chn][8 wn] = 16 KB
        if (lr == 0) {
            #pragma unroll
            for (int m = 0; m < 4; ++m)
                #pragma unroll
                for (int rg = 0; rg < 4; ++rg) {
                    const int x = m*16 + lg*4 + rg;
                    #pragma unroll
                    for (int c = 0; c < 4; ++c)
                        det[((mw*64 + x)*4 + c)*8 + wn] = p[c][m*4 + rg];
                }
        }
        __syncthreads();
        if (tid < 512) {
            const int vox = tid >> 2, chn = tid & 3;
            const float* dp = det + ((size_t)(vox*4 + chn))*8;
            float s = dp[0] + dp[1] + dp[2] + dp[3] + dp[4] + dp[5] + dp[6] + dp[7];
            const int ygl = y0 + (vox >> 6), x = vox & 63;
            const int vg = (z*Hy + ygl)*Wx + x;
            if (chn == 0) {
                float logit = s + blog[0];
                float score = 1.f/(1.f + expf(-logit));
                unsigned sb = f2sort(score);
                keys[vg] = ((unsigned long long)sb << 32)
                         | (unsigned long long)(0xFFFFFFFFu - (unsigned)vg);
                atomicAdd(&hist[sb >> 16], 1u);
            } else {
                float coord = (chn == 1) ? (float)z : (chn == 2) ? (float)ygl : (float)x;
                float loc = (coord + 0.5f)*4.0f + (s + breg[chn-1])*4.0f;
                locs[(size_t)vg*3 + (chn-1)] = loc;
            }
        }
    }
}

// --------------------------- selection / NMS tail ---------------------------
// Parallel cut finder over 64K buckets: suffix sums via Hillis-Steele scan.
__global__ __launch_bounds__(1024) void find_cut_kernel(const unsigned* __restrict__ hist,
                                                        unsigned* __restrict__ cutp) {
    __shared__ unsigned ps[1024];
    __shared__ unsigned fs[64];
    __shared__ int sh_cb;
    __shared__ unsigned sh_acc;
    int t = threadIdx.x;
    unsigned s = 0;
    const unsigned* hp = hist + (size_t)t*64;
    for (int j = 0; j < 64; ++j) s += hp[j];
    ps[t] = s;
    __syncthreads();
    for (int off = 1; off < 1024; off <<= 1) {
        unsigned v = ps[t] + ((t + off < 1024) ? ps[t + off] : 0u);
        __syncthreads();
        ps[t] = v;
        __syncthreads();
    }
    // ps[t] = suffix count of buckets >= t*64 ; non-increasing, ps[0] = NVOX
    if (ps[t] >= TOPK && (t == 1023 || ps[t+1] < TOPK)) {
        sh_cb = t; sh_acc = (t == 1023) ? 0u : ps[t+1];
    }
    __syncthreads();
    int cb = sh_cb; unsigned acc = sh_acc;
    if (t < 64) {
        unsigned f = acc;
        for (int u = t; u < 64; ++u) f += hist[(size_t)cb*64 + u];
        fs[t] = f;
    }
    __syncthreads();
    if (t < 64) {
        if (fs[t] >= TOPK && (t == 63 || fs[t+1] < TOPK))
            cutp[0] = ((unsigned)(cb*64 + t)) << 16;
    }
}

__global__ void compact_kernel(const unsigned long long* __restrict__ keys,
                               const unsigned* __restrict__ cutp,
                               unsigned* __restrict__ counter,
                               unsigned long long* __restrict__ cand) {
    int i = blockIdx.x*blockDim.x + threadIdx.x;
    unsigned thr = cutp[0];
    unsigned long long k = keys[i];
    if ((unsigned)(k >> 32) >= thr) {
        unsigned p = atomicAdd(counter, 1u);
        if (p < CAND_CAP) cand[p] = k;
    }
}

// Rank sort (keys unique): scatter packed (z,y,x,score) by exact rank.
__global__ __launch_bounds__(128) void rank_kernel(const unsigned* __restrict__ counter,
        const unsigned long long* __restrict__ cand, const float* __restrict__ locs,
        float4* __restrict__ loc4G) {
    __shared__ unsigned long long kbuf[CAND_CAP];   // 32 KB
    int t = threadIdx.x;
    int g = blockIdx.x*128 + t;
    int M = (int)*counter; if (M > CAND_CAP) M = CAND_CAP;
    for (int i = t; i < CAND_CAP; i += 128) kbuf[i] = (i < M) ? cand[i] : 0ull;
    __syncthreads();
    if (g >= M) return;
    unsigned long long mykey = kbuf[g];
    int rank = 0;
    for (int j = 0; j < M; ++j) rank += (kbuf[j] > mykey) ? 1 : 0;
    if (rank < TOPK) {
        unsigned idx = 0xFFFFFFFFu - (unsigned)(mykey & 0xFFFFFFFFull);
        float4 v;
        v.x = locs[(size_t)idx*3 + 0];
        v.y = locs[(size_t)idx*3 + 1];
        v.z = locs[(size_t)idx*3 + 2];
        v.w = sort2f((unsigned)(mykey >> 32));
        loc4G[rank] = v;
    }
}

// Neighbor lists within NMS radius (candidates vs all, LDS broadcast scan).
__global__ __launch_bounds__(64) void nbr_kernel(const float4* __restrict__ loc4G,
        unsigned short* __restrict__ nbidx, unsigned char* __restrict__ nbcnt) {
    __shared__ float4 b4[TOPK];   // 32 KB
    int t = threadIdx.x;
    int g = blockIdx.x*64 + t;
    for (int i = t; i < TOPK; i += 64) b4[i] = loc4G[i];
    __syncthreads();
    float4 me = b4[g];
    int cnt = 0;
    for (int j = 0; j < TOPK; ++j) {
        float4 o = b4[j];
        float dz = o.x - me.x, dy = o.y - me.y, dx = o.z - me.z;
        float d2 = dz*dz + dy*dy + dx*dx;
        if (d2 < 64.0f && j != g) {
            if (cnt < NBCAP) nbidx[(size_t)g*NBCAP + cnt] = (unsigned short)j;
            cnt++;
        }
    }
    nbcnt[g] = (unsigned char)min(cnt, 255);
}

// Greedy NMS via neighbor lists, wave-synchronous serial chain, early
// termination at 256 keeps (later flags provably can't affect output).
__global__ __launch_bounds__(512) void nms_kernel(const float4* __restrict__ loc4G,
        const unsigned short* __restrict__ nbidx, const unsigned char* __restrict__ nbcnt,
        const int* __restrict__ mask, float* __restrict__ out) {
    __shared__ float4 p4[TOPK];                 // 32 KB
    __shared__ unsigned short snb[TOPK*NBCAP];  // 64 KB
    __shared__ unsigned char scnt[TOPK];
    __shared__ unsigned char supf[TOPK];
    __shared__ unsigned char keepB[TOPK];
    __shared__ unsigned keepw[64];
    __shared__ int wpre[64];
    __shared__ int sh_nk;
    int t = threadIdx.x;
    for (int i = t; i < TOPK; i += 512) {
        p4[i] = loc4G[i]; scnt[i] = nbcnt[i]; supf[i] = 0; keepB[i] = 0;
    }
    for (int i = t; i < TOPK*NBCAP/8; i += 512)
        ((uint4*)snb)[i] = ((const uint4*)nbidx)[i];
    __syncthreads();
    if (t < 64) {
        const int l = t;
        float cz[32], cy[32], cx[32];   // fallback cache (overflowed nbr lists)
        #pragma unroll
        for (int j = 0; j < 32; ++j) {
            float4 v = p4[l*32 + j];
            cz[j] = v.x; cy[j] = v.y; cx[j] = v.z;
        }
        int myok = 0;
        #pragma unroll
        for (int j = 0; j < 32; ++j) myok += (p4[l*32 + j].w >= 0.2f) ? 1 : 0;
        #pragma unroll
        for (int s = 1; s < 64; s <<= 1) myok += __shfl_xor(myok, s, 64);
        const int NS = myok;            // scores sorted desc -> prefix
        int keeps = 0;
        for (int i = 0; i < NS; ++i) {
            bool kept = (supf[i] == 0);
            if (kept) {
                if (l == 0) keepB[i] = 1;
                ++keeps;
                const int cnt = scnt[i];
                if (cnt <= NBCAP) {
                    if (l < cnt) supf[snb[i*NBCAP + l]] = 1;
                } else {
                    float4 pv = p4[i];
                    #pragma unroll
                    for (int j = 0; j < 32; ++j) {
                        float dz = cz[j]-pv.x, dy = cy[j]-pv.y, dx = cx[j]-pv.z;
                        if (dz*dz + dy*dy + dx*dx < 64.0f) supf[l*32 + j] = 1;
                    }
                }
                asm volatile("s_waitcnt lgkmcnt(0)" ::: "memory");
                if (keeps >= MAXOUT) break;
            }
        }
    }
    __syncthreads();
    if (t < 64) {
        unsigned wmask = 0u;
        for (int j = 0; j < 32; ++j) wmask |= (keepB[t*32 + j] ? 1u : 0u) << j;
        keepw[t] = wmask;
    }
    __syncthreads();
    if (t < 64) {
        int p = 0;
        for (int j = 0; j < t; ++j) p += __popc(keepw[j]);
        wpre[t] = p;
        if (t == 63) sh_nk = p + __popc(keepw[63]);
    }
    __syncthreads();
    const int nk = sh_nk;
    for (int i = t; i < TOPK; i += 512) {
        unsigned w = keepw[i >> 5];
        bool kp = (w >> (i & 31)) & 1u;
        int rk = wpre[i >> 5] + __popc(w & ((1u << (i & 31)) - 1u));
        int slot = kp ? rk : (nk + (i - rk));
        if (slot < MAXOUT) {
            float4 v = p4[i];
            float lz = v.x, ly = v.y, lx = v.z;
            float sc = kp ? v.w : 0.f;
            int iz = (int)floorf(lz), iy = (int)floorf(ly), ix = (int)floorf(lx);
            int cz2 = min(max(iz,0),Dz*4-1), cy2 = min(max(iy,0),Hy*4-1), cx2 = min(max(ix,0),Wx*4-1);
            bool inr = (iz==cz2) && (iy==cy2) && (ix==cx2);
            float osc = (inr && mask[((size_t)cz2*(Hy*4) + cy2)*(Wx*4) + cx2] != 0) ? sc : 0.f;
            out[slot*4+0] = lz; out[slot*4+1] = ly; out[slot*4+2] = lx; out[slot*4+3] = osc;
        }
    }
}

extern "C" void kernel_launch(void* const* d_in, const int* in_sizes, int n_in,
                              void* d_out, int out_size, void* d_ws, size_t ws_size,
                              hipStream_t stream) {
    const float* feature = (const float*)d_in[0];
    const int*   mask    = (const int*)d_in[1];
    const float* w0   = (const float*)d_in[2];
    const float* b0   = (const float*)d_in[3];
    const float* w1   = (const float*)d_in[4];
    const float* b1   = (const float*)d_in[5];
    const float* wlog = (const float*)d_in[6];
    const float* blog = (const float*)d_in[7];
    const float* wreg = (const float*)d_in[8];
    const float* breg = (const float*)d_in[9];

    char* ws = (char*)d_ws;
    size_t off = 0;
    unsigned short* h1hi = (unsigned short*)(ws + off); off += (size_t)NVOX*CHN*2;  // 33.5 MB
    unsigned short* h1lo = (unsigned short*)(ws + off); off += (size_t)NVOX*CHN*2;  // 33.5 MB
    u16x8* wpk0 = (u16x8*)(ws + off);               off += (size_t)442368*16;       // 7.1 MB
    u16x8* wpk1 = (u16x8*)(ws + off);               off += (size_t)442368*16;       // 7.1 MB
    unsigned long long* keys = (unsigned long long*)(ws + off); off += (size_t)NVOX*8;
    float* locs = (float*)(ws + off);               off += (size_t)NVOX*3*4;
    unsigned* hist = (unsigned*)(ws + off);         off += (size_t)NHIST*4;         // 256 KB
    unsigned* counter = (unsigned*)(ws + off);      off += 256;
    unsigned* cutp = counter + 1;
    unsigned long long* cand = (unsigned long long*)(ws + off); off += (size_t)CAND_CAP*8;
    float4* loc4G = (float4*)(ws + off);            off += (size_t)TOPK*16;
    unsigned short* nbidx = (unsigned short*)(ws + off); off += (size_t)TOPK*NBCAP*2;
    unsigned char* nbcnt = (unsigned char*)(ws + off);   off += (size_t)TOPK;
    if (ws_size < off) return;   // scratch too small: fail loudly (poison output)

    prep_kernel<<<1792, 256, 0, stream>>>(w0, w1, wpk0, wpk1, hist, counter);
    dim3 cgrid(Hy/2, Dz);
    conv_kernel<0><<<cgrid, 1024, 0, stream>>>(feature, nullptr, nullptr, wpk0, b0,
                                               h1hi, h1lo,
                                               nullptr, nullptr, nullptr, nullptr,
                                               nullptr, nullptr, nullptr);
    conv_kernel<1><<<cgrid, 1024, 0, stream>>>(nullptr, h1hi, h1lo, wpk1, b1,
                                               nullptr, nullptr,
                                               wlog, blog, wreg, breg,
                                               locs, keys, hist);
    find_cut_kernel<<<1, 1024, 0, stream>>>(hist, cutp);
    compact_kernel<<<NVOX/256, 256, 0, stream>>>(keys, cutp, counter, cand);
    rank_kernel<<<CAND_CAP/128, 128, 0, stream>>>(counter, cand, locs, loc4G);
    nbr_kernel<<<TOPK/64, 64, 0, stream>>>(loc4G, nbidx, nbcnt);
    nms_kernel<<<1, 512, 0, stream>>>(loc4G, nbidx, nbcnt, mask, (float*)d_out);
}